// Round 10
// baseline (1046.869 us; speedup 1.0000x reference)
//
#include <hip/hip_runtime.h>

typedef short short8 __attribute__((ext_vector_type(8)));
typedef float f32x4 __attribute__((ext_vector_type(4)));
typedef unsigned short u16;

static constexpr int BATCH = 2, S = 2048, H = 4096, NHEAD = 32, HDIM = 128;

__device__ __forceinline__ u16 f2b(float f) {
  union { float f; unsigned u; } v; v.f = f;
  return (u16)((v.u + 0x7fffu + ((v.u >> 16) & 1u)) >> 16);
}
__device__ __forceinline__ float b2f(u16 h) {
  union { unsigned u; float f; } v; v.u = ((unsigned)h) << 16;
  return v.f;
}

__device__ __forceinline__ void gl16(const u16* g, u16* l) {
  __builtin_amdgcn_global_load_lds((__attribute__((address_space(1))) void*)g,
                                   (__attribute__((address_space(3))) void*)l,
                                   16, 0, 0);
}

#define MFMA(acc, a, b) \
  acc = __builtin_amdgcn_mfma_f32_16x16x32_bf16(a, b, acc, 0, 0, 0)

// ---- f32 -> bf16 convert, 4 elems/thread, exact grid ----
__global__ __launch_bounds__(256) void cvt_bf16(const float* __restrict__ in,
                                                u16* __restrict__ out) {
  size_t i = ((size_t)blockIdx.x * 256 + threadIdx.x) * 4;
  float4 v = *(const float4*)(in + i);
  ushort4 o = { f2b(v.x), f2b(v.y), f2b(v.z), f2b(v.w) };
  *(ushort4*)(out + i) = o;
}

// ---- 256x256 NT GEMM, 4 phases/K-tile, BK=64, 8 waves (2x4).
// r10 schedule: BALANCED 1 half-tile staged per phase (r8 property) with
// min 2-phase latency cover (r9 goal): f1:A0(t+1), f2:A1(t+1) -> cur^1;
// f3:B0(t+2), f4:B1(t+2) -> cur (B free after f2); single vmcnt(4) @f4
// drains t+1's 4 halves (cover 5/4/3/2 phases), leaves B(t+2) in flight.
template <bool F32OUT>
__global__ __launch_bounds__(512, 2) void gemm256(const u16* __restrict__ A,
                                                  const u16* __restrict__ B,
                                                  void* __restrict__ C,
                                                  int M, int N, int K) {
  __shared__ u16 AL[2][2][128 * 64];
  __shared__ u16 BL[2][2][128 * 64];
  const int nbn = N >> 8;
  const int nwg = (M >> 8) * nbn;
  const int bid = blockIdx.x;
  const int wg = (bid & 7) * (nwg >> 3) + (bid >> 3);  // XCD swizzle (nwg%8==0)
  const int bm = wg / nbn, bn = wg % nbn;
  const int tid = threadIdx.x, lane = tid & 63;
  const int w = tid >> 6, wm = w >> 2, wn = w & 3;
  const int hi = lane >> 4, lo = lane & 15;
  const int nk = K >> 6;

  const u16* Abase = A + (size_t)(bm * 256) * K;
  const u16* Bbase = B + (size_t)(bn * 256) * K;

#define STG_A(buf, half, kt)                                                   \
  { _Pragma("unroll") for (int i = 0; i < 2; ++i) {                            \
      int c = tid + i * 512, r = c >> 3, s = c & 7;                            \
      gl16(Abase + (size_t)((half) * 128 + r) * K + (kt) * 64 +                \
               ((s ^ (r & 7)) * 8),                                            \
           &AL[buf][half][c * 8]);                                             \
    } }
#define STG_B(buf, half, kt)                                                   \
  { _Pragma("unroll") for (int i = 0; i < 2; ++i) {                            \
      int c = tid + i * 512, r = c >> 3, s = c & 7;                            \
      gl16(Bbase + (size_t)((half) * 128 + r) * K + (kt) * 64 +                \
               ((s ^ (r & 7)) * 8),                                            \
           &BL[buf][half][c * 8]);                                             \
    } }
#define LGKM0()                                                                \
  do { asm volatile("s_waitcnt lgkmcnt(0)" ::: "memory");                      \
       __builtin_amdgcn_sched_barrier(0); } while (0)

  f32x4 acc[8][4] = {};

  // prologue: tile0 fully + B halves of tile1; drain tile0, leave B(1)
  STG_A(0, 0, 0) STG_A(0, 1, 0) STG_B(0, 0, 0) STG_B(0, 1, 0)
  if (nk > 1) {
    STG_B(1, 0, 1) STG_B(1, 1, 1)
    asm volatile("s_waitcnt vmcnt(4)" ::: "memory");
  } else {
    asm volatile("s_waitcnt vmcnt(0)" ::: "memory");
  }
  __builtin_amdgcn_sched_barrier(0);
  __builtin_amdgcn_s_barrier();

  short8 af[4][2], bf[2][2][2];  // af[mi][ks]; bf[nh][ni][ks]

  for (int t = 0; t < nk; ++t) {
    const int cur = t & 1;
    const u16* Awave = &AL[cur][wm][0];
    const u16* Bwave = &BL[cur][wn >> 1][0];
    const int lrB = (wn & 1) * 64;

    // ---- f1: read A rows 0-63 (8 b128) + B nh0 (4 b128); stage A0(t+1)
#pragma unroll
    for (int mi = 0; mi < 4; ++mi)
#pragma unroll
      for (int ks = 0; ks < 2; ++ks)
        af[mi][ks] = *(const short8*)&Awave[(mi * 16 + lo) * 64 +
                                            (((ks * 4 + hi) ^ (lo & 7)) * 8)];
#pragma unroll
    for (int ni = 0; ni < 2; ++ni)
#pragma unroll
      for (int ks = 0; ks < 2; ++ks)
        bf[0][ni][ks] = *(const short8*)&Bwave[(lrB + ni * 16 + lo) * 64 +
                                               (((ks * 4 + hi) ^ (lo & 7)) * 8)];
    if (t + 1 < nk) STG_A(cur ^ 1, 0, t + 1)
    LGKM0();
    __builtin_amdgcn_s_barrier();
    __builtin_amdgcn_s_setprio(1);
#pragma unroll
    for (int mi = 0; mi < 4; ++mi)
#pragma unroll
      for (int ni = 0; ni < 2; ++ni)
#pragma unroll
        for (int ks = 0; ks < 2; ++ks)
          MFMA(acc[mi][ni], af[mi][ks], bf[0][ni][ks]);
    __builtin_amdgcn_s_setprio(0);
    __builtin_amdgcn_s_barrier();

    // ---- f2: read B nh1 (4 b128); stage A1(t+1)
#pragma unroll
    for (int ni = 0; ni < 2; ++ni)
#pragma unroll
      for (int ks = 0; ks < 2; ++ks)
        bf[1][ni][ks] = *(const short8*)&Bwave[(lrB + 32 + ni * 16 + lo) * 64 +
                                               (((ks * 4 + hi) ^ (lo & 7)) * 8)];
    if (t + 1 < nk) STG_A(cur ^ 1, 1, t + 1)
    LGKM0();
    __builtin_amdgcn_s_barrier();
    __builtin_amdgcn_s_setprio(1);
#pragma unroll
    for (int mi = 0; mi < 4; ++mi)
#pragma unroll
      for (int ni = 0; ni < 2; ++ni)
#pragma unroll
        for (int ks = 0; ks < 2; ++ks)
          MFMA(acc[mi][2 + ni], af[mi][ks], bf[1][ni][ks]);
    __builtin_amdgcn_s_setprio(0);
    __builtin_amdgcn_s_barrier();

    // ---- f3: read A rows 64-127 (8 b128); stage B0(t+2) into cur (B free)
#pragma unroll
    for (int mi = 0; mi < 4; ++mi)
#pragma unroll
      for (int ks = 0; ks < 2; ++ks)
        af[mi][ks] = *(const short8*)&Awave[((64 + mi * 16 + lo)) * 64 +
                                            (((ks * 4 + hi) ^ (lo & 7)) * 8)];
    if (t + 2 < nk) STG_B(cur, 0, t + 2)
    LGKM0();
    __builtin_amdgcn_s_barrier();
    __builtin_amdgcn_s_setprio(1);
#pragma unroll
    for (int mi = 0; mi < 4; ++mi)
#pragma unroll
      for (int ni = 0; ni < 2; ++ni)
#pragma unroll
        for (int ks = 0; ks < 2; ++ks)
          MFMA(acc[4 + mi][2 + ni], af[mi][ks], bf[1][ni][ks]);
    __builtin_amdgcn_s_setprio(0);
    __builtin_amdgcn_s_barrier();

    // ---- f4: no ds_read (reuse bf[0]); stage B1(t+2); counted vmcnt(4)
    if (t + 2 < nk) {
      STG_B(cur, 1, t + 2)
      asm volatile("s_waitcnt vmcnt(4)" ::: "memory");
    } else {
      asm volatile("s_waitcnt vmcnt(0)" ::: "memory");
    }
    __builtin_amdgcn_sched_barrier(0);
    __builtin_amdgcn_s_barrier();
    __builtin_amdgcn_s_setprio(1);
#pragma unroll
    for (int mi = 0; mi < 4; ++mi)
#pragma unroll
      for (int ni = 0; ni < 2; ++ni)
#pragma unroll
        for (int ks = 0; ks < 2; ++ks)
          MFMA(acc[4 + mi][ni], af[mi][ks], bf[0][ni][ks]);
    __builtin_amdgcn_s_setprio(0);
    __builtin_amdgcn_s_barrier();
  }

  // epilogue: row = bm*256+wm*128+mf*16+hi*4+j, col = bn*256+wn*64+nf*16+lo
#pragma unroll
  for (int mf = 0; mf < 8; ++mf)
#pragma unroll
    for (int nf = 0; nf < 4; ++nf)
#pragma unroll
      for (int j = 0; j < 4; ++j) {
        size_t idx = (size_t)(bm * 256 + wm * 128 + mf * 16 + hi * 4 + j) * N +
                     bn * 256 + wn * 64 + nf * 16 + lo;
        if (F32OUT) ((float*)C)[idx] = acc[mf][nf][j];
        else        ((u16*)C)[idx]   = f2b(acc[mf][nf][j]);
      }
}

// ---- RoPE + scatter: qkv[b][s][12288] -> q_r,k_r [b][nh][s][hd] ----
__global__ __launch_bounds__(256) void rope_qk(const u16* __restrict__ qkv,
                                               const int* __restrict__ pos,
                                               u16* __restrict__ qr,
                                               u16* __restrict__ kr) {
  __shared__ float cs[64], sn[64];
  const int bs = blockIdx.x;
  const int b = bs >> 11, s = bs & 2047;
  const int tid = threadIdx.x;
  if (tid < 64) {
    float p = (float)pos[bs];
    float freq = __powf(10000.0f, -(float)tid * (1.0f / 64.0f));
    float a = p * freq;
    sn[tid] = sinf(a);
    cs[tid] = cosf(a);
  }
  __syncthreads();
  const u16* src = qkv + (size_t)bs * 12288;
  for (int i = tid; i < 4096; i += 256) {
    int nh = i >> 7, hd = i & 127, f = hd & 63;
    float c = cs[f], sv = sn[f];
    int oth = (hd < 64) ? i + 64 : i - 64;
    size_t dst = ((size_t)(b * NHEAD + nh) * S + s) * HDIM + hd;
    float x = b2f(src[i]), xo = b2f(src[oth]);
    qr[dst] = f2b((hd < 64) ? (x * c - xo * sv) : (x * c + xo * sv));
    float xk = b2f(src[4096 + i]), xko = b2f(src[4096 + oth]);
    kr[dst] = f2b((hd < 64) ? (xk * c - xko * sv) : (xk * c + xko * sv));
  }
}

// ---- V -> MFMA-B-fragment order, per (bh, 64-kv block) ----
__global__ __launch_bounds__(256) void transpose_v(const u16* __restrict__ qkv,
                                                   u16* __restrict__ vt) {
  __shared__ u16 L[64 * 136];
  const int kb = blockIdx.x & 31, bh = blockIdx.x >> 5;
  const int b = bh >> 5, nh = bh & 31;
  const int tid = threadIdx.x;
  const u16* src = qkv + ((size_t)(b * S + kb * 64)) * 12288 + 8192 + nh * 128;
#pragma unroll
  for (int i = 0; i < 4; ++i) {
    int idx = i * 256 + tid, r = idx >> 4, gd = idx & 15;
    *(uint4*)&L[r * 136 + gd * 8] = *(const uint4*)(src + (size_t)r * 12288 + gd * 8);
  }
  __syncthreads();
  u16* dst = vt + ((size_t)bh * S + kb * 64) * 128;
#pragma unroll
  for (int i = 0; i < 4; ++i) {
    int idx = i * 256 + tid;
    int f = idx >> 6, l = idx & 63;
    int ks2 = f >> 3, db = f & 7, hi = l >> 4, lo = l & 15;
    int d = db * 16 + lo;
    int rb = (ks2 * 32 + hi * 8) * 136 + d;
    unsigned e0 = L[rb], e1 = L[rb + 136], e2 = L[rb + 272], e3 = L[rb + 408];
    unsigned e4 = L[rb + 544], e5 = L[rb + 680], e6 = L[rb + 816], e7 = L[rb + 952];
    uint4 o; o.x = e0 | (e1 << 16); o.y = e2 | (e3 << 16);
    o.z = e4 | (e5 << 16); o.w = e6 | (e7 << 16);
    *(uint4*)(dst + (size_t)idx * 8) = o;
  }
}

// ---- flash attention fwd, causal. QBLK=128: 1 block = (b,h,128 q-rows),
// 8 waves x 16 rows, 512 thr. Halves staging count vs QBLK=64 (272 vs 528
// tiles per bh) and doubles waves/CU. KV tile = 64 rows, double-buffered
// DMA, counted vmcnt(4). LDS 80KB -> 2 blocks/CU.
__global__ __launch_bounds__(512, 2) void flash_fwd(const u16* __restrict__ q,
                                                    const u16* __restrict__ k,
                                                    const u16* __restrict__ vt,
                                                    u16* __restrict__ o) {
  __shared__ u16 KB[2][64 * 128];
  __shared__ u16 VB[2][64 * 128];
  __shared__ u16 Ps[8][16 * 64];
  const int nqt = S / 128;
  const int qt = (nqt - 1) - ((int)blockIdx.x % nqt);  // heavy blocks first
  const int bh = blockIdx.x / nqt;
  const int tid = threadIdx.x, lane = tid & 63, w = tid >> 6;
  const int hi = lane >> 4, lo = lane & 15;

  const u16* qg = q + ((size_t)bh * S + qt * 128 + w * 16) * HDIM;
  short8 qf[4];
#pragma unroll
  for (int ks = 0; ks < 4; ++ks) {
    short8 r = *(const short8*)(qg + (size_t)lo * HDIM + ks * 32 + hi * 8);
    union { short8 s; u16 u[8]; } t; t.s = r;
#pragma unroll
    for (int e = 0; e < 8; ++e)
      t.u[e] = f2b(b2f(t.u[e]) * 0.08838834764831845f);
    qf[ks] = t.s;
  }

  float m_i[4], l_i[4];
  f32x4 oacc[8] = {};
#pragma unroll
  for (int j = 0; j < 4; ++j) { m_i[j] = -1e30f; l_i[j] = 0.0f; }

  const u16* kg = k + (size_t)bh * S * HDIM;
  const u16* vg = vt + (size_t)bh * S * HDIM;

  // per-thread: 2 gl16 K + 2 gl16 V per tile
#define STAGE(buf, kvbase)                                                  \
  {                                                                         \
    _Pragma("unroll") for (int i = 0; i < 2; ++i) {                         \
      int idx = i * 512 + tid, r = idx >> 4, gd = idx & 15;                 \
      gl16(kg + (size_t)((kvbase) + r) * HDIM + ((gd ^ (r & 7)) * 8),       \
           &KB[buf][idx * 8]);                                              \
    }                                                                       \
    _Pragma("unroll") for (int i = 0; i < 2; ++i) {                         \
      int idx = i * 512 + tid;                                              \
      gl16(vg + (size_t)(kvbase) * HDIM + idx * 8, &VB[buf][idx * 8]);      \
    }                                                                       \
  }

  const int nkv = 2 * qt + 2;  // kv tiles of 64 covering rows <= qt*128+127
  STAGE(0, 0)
  int cur = 0;
  u16* PsW = &Ps[w][0];

  for (int kvt = 0; kvt < nkv; ++kvt) {
    if (kvt + 1 < nkv) {
      STAGE(cur ^ 1, (kvt + 1) * 64)
      asm volatile("s_waitcnt vmcnt(4)" ::: "memory");
    } else {
      asm volatile("s_waitcnt vmcnt(0)" ::: "memory");
    }
    __builtin_amdgcn_s_barrier();
    __builtin_amdgcn_sched_barrier(0);
    const u16* Kc = &KB[cur][0];
    const u16* Vc = &VB[cur][0];

    f32x4 sc[4] = {};
#pragma unroll
    for (int ks = 0; ks < 4; ++ks) {
      const int colu = ks * 32 + hi * 8;
#pragma unroll
      for (int cb = 0; cb < 4; ++cb) {
        const int row = cb * 16 + lo;
        short8 kf = *(const short8*)&Kc[row * 128 + (colu ^ ((row & 7) << 3))];
        MFMA(sc[cb], qf[ks], kf);
      }
    }

    const int qrow = qt * 128 + w * 16 + hi * 4;
    const bool diag = (kvt >= 2 * qt + (w >> 2));  // tiles that can mask this wave
#pragma unroll
    for (int cb = 0; cb < 4; ++cb) {
      const int kvc = kvt * 64 + cb * 16 + lo;
#pragma unroll
      for (int j = 0; j < 4; ++j) {
        float sv = sc[cb][j];
        if (diag && kvc > qrow + j) sv = -1e30f;
        sc[cb][j] = sv;
      }
    }
    float rmax[4], rs[4];
#pragma unroll
    for (int j = 0; j < 4; ++j) {
      rmax[j] = fmaxf(fmaxf(sc[0][j], sc[1][j]), fmaxf(sc[2][j], sc[3][j]));
      for (int d = 8; d; d >>= 1) rmax[j] = fmaxf(rmax[j], __shfl_xor(rmax[j], d));
      float mn = fmaxf(m_i[j], rmax[j]);
      float sf = __expf(m_i[j] - mn);
      m_i[j] = mn; l_i[j] *= sf;
#pragma unroll
      for (int db = 0; db < 8; ++db) oacc[db][j] *= sf;
      rs[j] = 0.0f;
    }
#pragma unroll
    for (int cb = 0; cb < 4; ++cb)
#pragma unroll
      for (int j = 0; j < 4; ++j) {
        float p = __expf(sc[cb][j] - m_i[j]);
        sc[cb][j] = p; rs[j] += p;
      }
#pragma unroll
    for (int j = 0; j < 4; ++j) {
      for (int d = 8; d; d >>= 1) rs[j] += __shfl_xor(rs[j], d);
      l_i[j] += rs[j];
    }

#pragma unroll
    for (int cb = 0; cb < 4; ++cb)
#pragma unroll
      for (int j = 0; j < 4; ++j) {
        const int p = hi * 4 + j;
        PsW[p * 64 + ((cb * 16 + lo) ^ ((p & 7) << 3))] = f2b(sc[cb][j]);
      }
    short8 pf0 = *(const short8*)&PsW[lo * 64 + ((hi * 8) ^ ((lo & 7) << 3))];
    short8 pf1 = *(const short8*)&PsW[lo * 64 + ((32 + hi * 8) ^ ((lo & 7) << 3))];

#pragma unroll
    for (int ks2 = 0; ks2 < 2; ++ks2) {
      const short8 pf = ks2 ? pf1 : pf0;
#pragma unroll
      for (int db = 0; db < 8; ++db) {
        short8 vf = *(const short8*)&Vc[((ks2 * 8 + db) * 64 + lane) * 8];
        MFMA(oacc[db], pf, vf);
      }
    }
    __builtin_amdgcn_s_barrier();
    cur ^= 1;
  }

#pragma unroll
  for (int j = 0; j < 4; ++j) {
    float inv = 1.0f / l_i[j];
    int srow = qt * 128 + w * 16 + hi * 4 + j;
    const int b = bh >> 5, nh = bh & 31;
    size_t base = ((size_t)b * S + srow) * H + (size_t)nh * HDIM + lo;
#pragma unroll
    for (int db = 0; db < 8; ++db)
      o[base + db * 16] = f2b(oacc[db][j] * inv);
  }
}

extern "C" void kernel_launch(void* const* d_in, const int* in_sizes, int n_in,
                              void* d_out, int out_size, void* d_ws, size_t ws_size,
                              hipStream_t stream) {
  const int* pos = (const int*)d_in[0];
  const float* hs = (const float*)d_in[1];
  const float* wpack = (const float*)d_in[2];
  const float* wo = (const float*)d_in[3];
  float* out = (float*)d_out;
  char* ws = (char*)d_ws;
  u16* hs_b    = (u16*)(ws + 0UL);          // dead after gemm1 -> reused as v_t
  u16* wpack_b = (u16*)(ws + 33554432UL);
  u16* wo_b    = (u16*)(ws + 134217728UL);
  u16* qkv_b   = (u16*)(ws + 167772160UL);
  u16* q_r     = (u16*)(ws + 268435456UL);
  u16* k_r     = (u16*)(ws + 301989888UL);
  u16* attn_b  = (u16*)(ws + 335544320UL);
  u16* v_t     = hs_b;

  cvt_bf16<<<16384, 256, 0, stream>>>(hs, hs_b);
  cvt_bf16<<<49152, 256, 0, stream>>>(wpack, wpack_b);
  cvt_bf16<<<16384, 256, 0, stream>>>(wo, wo_b);
  gemm256<false><<<768, 512, 0, stream>>>(hs_b, wpack_b, qkv_b, 4096, 12288, 4096);
  rope_qk<<<4096, 256, 0, stream>>>(qkv_b, pos, q_r, k_r);
  transpose_v<<<2048, 256, 0, stream>>>(qkv_b, v_t);
  flash_fwd<<<16 * 64, 512, 0, stream>>>(q_r, k_r, v_t, attn_b);
  gemm256<true><<<256, 512, 0, stream>>>(attn_b, wo_b, out, 4096, 4096, 4096);
}

// Round 11
// 964.781 us; speedup vs baseline: 1.0851x; 1.0851x over previous
//
#include <hip/hip_runtime.h>

typedef short short8 __attribute__((ext_vector_type(8)));
typedef float f32x4 __attribute__((ext_vector_type(4)));
typedef unsigned short u16;

static constexpr int BATCH = 2, S = 2048, H = 4096, NHEAD = 32, HDIM = 128;

__device__ __forceinline__ u16 f2b(float f) {
  union { float f; unsigned u; } v; v.f = f;
  return (u16)((v.u + 0x7fffu + ((v.u >> 16) & 1u)) >> 16);
}
__device__ __forceinline__ float b2f(u16 h) {
  union { unsigned u; float f; } v; v.u = ((unsigned)h) << 16;
  return v.f;
}

__device__ __forceinline__ void gl16(const u16* g, u16* l) {
  __builtin_amdgcn_global_load_lds((__attribute__((address_space(1))) void*)g,
                                   (__attribute__((address_space(3))) void*)l,
                                   16, 0, 0);
}

#define MFMA(acc, a, b) \
  acc = __builtin_amdgcn_mfma_f32_16x16x32_bf16(a, b, acc, 0, 0, 0)

// ---- f32 -> bf16 convert, 4 elems/thread, exact grid ----
__global__ __launch_bounds__(256) void cvt_bf16(const float* __restrict__ in,
                                                u16* __restrict__ out) {
  size_t i = ((size_t)blockIdx.x * 256 + threadIdx.x) * 4;
  float4 v = *(const float4*)(in + i);
  ushort4 o = { f2b(v.x), f2b(v.y), f2b(v.z), f2b(v.w) };
  *(ushort4*)(out + i) = o;
}

// ---- 256x256 NT GEMM, 4 phases/K-tile, BK=64, 8 waves (2x4).
// r11: m201 phase ordering — {ds_read issue; stage} -> s_barrier ->
// lgkmcnt(0) -> MFMA. Read latency hides under barrier rendezvous instead
// of adding serially before it. Stage placement (r10): f1:A0(t+1),
// f2:A1(t+1) -> cur^1; f3:B0(t+2), f4:B1(t+2) -> cur; vmcnt(4) @f4.
template <bool F32OUT>
__global__ __launch_bounds__(512, 2) void gemm256(const u16* __restrict__ A,
                                                  const u16* __restrict__ B,
                                                  void* __restrict__ C,
                                                  int M, int N, int K) {
  __shared__ u16 AL[2][2][128 * 64];
  __shared__ u16 BL[2][2][128 * 64];
  const int nbn = N >> 8;
  const int nwg = (M >> 8) * nbn;
  const int bid = blockIdx.x;
  const int wg = (bid & 7) * (nwg >> 3) + (bid >> 3);  // XCD swizzle (nwg%8==0)
  const int bm = wg / nbn, bn = wg % nbn;
  const int tid = threadIdx.x, lane = tid & 63;
  const int w = tid >> 6, wm = w >> 2, wn = w & 3;
  const int hi = lane >> 4, lo = lane & 15;
  const int nk = K >> 6;

  const u16* Abase = A + (size_t)(bm * 256) * K;
  const u16* Bbase = B + (size_t)(bn * 256) * K;

#define STG_A(buf, half, kt)                                                   \
  { _Pragma("unroll") for (int i = 0; i < 2; ++i) {                            \
      int c = tid + i * 512, r = c >> 3, s = c & 7;                            \
      gl16(Abase + (size_t)((half) * 128 + r) * K + (kt) * 64 +                \
               ((s ^ (r & 7)) * 8),                                            \
           &AL[buf][half][c * 8]);                                             \
    } }
#define STG_B(buf, half, kt)                                                   \
  { _Pragma("unroll") for (int i = 0; i < 2; ++i) {                            \
      int c = tid + i * 512, r = c >> 3, s = c & 7;                            \
      gl16(Bbase + (size_t)((half) * 128 + r) * K + (kt) * 64 +                \
               ((s ^ (r & 7)) * 8),                                            \
           &BL[buf][half][c * 8]);                                             \
    } }
#define LGKM0()                                                                \
  do { asm volatile("s_waitcnt lgkmcnt(0)" ::: "memory");                      \
       __builtin_amdgcn_sched_barrier(0); } while (0)
#define PREBAR()                                                               \
  do { __builtin_amdgcn_sched_barrier(0);                                      \
       __builtin_amdgcn_s_barrier(); } while (0)

  f32x4 acc[8][4] = {};

  // prologue: tile0 fully + B halves of tile1; drain tile0, leave B(1)
  STG_A(0, 0, 0) STG_A(0, 1, 0) STG_B(0, 0, 0) STG_B(0, 1, 0)
  if (nk > 1) {
    STG_B(1, 0, 1) STG_B(1, 1, 1)
    asm volatile("s_waitcnt vmcnt(4)" ::: "memory");
  } else {
    asm volatile("s_waitcnt vmcnt(0)" ::: "memory");
  }
  __builtin_amdgcn_sched_barrier(0);
  __builtin_amdgcn_s_barrier();

  short8 af[4][2], bf[2][2][2];  // af[mi][ks]; bf[nh][ni][ks]

  for (int t = 0; t < nk; ++t) {
    const int cur = t & 1;
    const u16* Awave = &AL[cur][wm][0];
    const u16* Bwave = &BL[cur][wn >> 1][0];
    const int lrB = (wn & 1) * 64;

    // ---- f1: issue A rows 0-63 (8 b128) + B nh0 (4 b128); stage A0(t+1)
#pragma unroll
    for (int mi = 0; mi < 4; ++mi)
#pragma unroll
      for (int ks = 0; ks < 2; ++ks)
        af[mi][ks] = *(const short8*)&Awave[(mi * 16 + lo) * 64 +
                                            (((ks * 4 + hi) ^ (lo & 7)) * 8)];
#pragma unroll
    for (int ni = 0; ni < 2; ++ni)
#pragma unroll
      for (int ks = 0; ks < 2; ++ks)
        bf[0][ni][ks] = *(const short8*)&Bwave[(lrB + ni * 16 + lo) * 64 +
                                               (((ks * 4 + hi) ^ (lo & 7)) * 8)];
    if (t + 1 < nk) STG_A(cur ^ 1, 0, t + 1)
    PREBAR();   // rendezvous while ds_reads in flight
    LGKM0();    // drain after barrier (m201 order)
    __builtin_amdgcn_s_setprio(1);
#pragma unroll
    for (int mi = 0; mi < 4; ++mi)
#pragma unroll
      for (int ni = 0; ni < 2; ++ni)
#pragma unroll
        for (int ks = 0; ks < 2; ++ks)
          MFMA(acc[mi][ni], af[mi][ks], bf[0][ni][ks]);
    __builtin_amdgcn_s_setprio(0);
    __builtin_amdgcn_s_barrier();

    // ---- f2: issue B nh1 (4 b128); stage A1(t+1)
#pragma unroll
    for (int ni = 0; ni < 2; ++ni)
#pragma unroll
      for (int ks = 0; ks < 2; ++ks)
        bf[1][ni][ks] = *(const short8*)&Bwave[(lrB + 32 + ni * 16 + lo) * 64 +
                                               (((ks * 4 + hi) ^ (lo & 7)) * 8)];
    if (t + 1 < nk) STG_A(cur ^ 1, 1, t + 1)
    PREBAR();
    LGKM0();
    __builtin_amdgcn_s_setprio(1);
#pragma unroll
    for (int mi = 0; mi < 4; ++mi)
#pragma unroll
      for (int ni = 0; ni < 2; ++ni)
#pragma unroll
        for (int ks = 0; ks < 2; ++ks)
          MFMA(acc[mi][2 + ni], af[mi][ks], bf[1][ni][ks]);
    __builtin_amdgcn_s_setprio(0);
    __builtin_amdgcn_s_barrier();

    // ---- f3: issue A rows 64-127 (8 b128); stage B0(t+2) into cur (B free)
#pragma unroll
    for (int mi = 0; mi < 4; ++mi)
#pragma unroll
      for (int ks = 0; ks < 2; ++ks)
        af[mi][ks] = *(const short8*)&Awave[((64 + mi * 16 + lo)) * 64 +
                                            (((ks * 4 + hi) ^ (lo & 7)) * 8)];
    if (t + 2 < nk) STG_B(cur, 0, t + 2)
    PREBAR();
    LGKM0();
    __builtin_amdgcn_s_setprio(1);
#pragma unroll
    for (int mi = 0; mi < 4; ++mi)
#pragma unroll
      for (int ni = 0; ni < 2; ++ni)
#pragma unroll
        for (int ks = 0; ks < 2; ++ks)
          MFMA(acc[4 + mi][2 + ni], af[mi][ks], bf[1][ni][ks]);
    __builtin_amdgcn_s_setprio(0);
    __builtin_amdgcn_s_barrier();

    // ---- f4: no ds_read (reuse bf[0]); stage B1(t+2); counted vmcnt(4)
    if (t + 2 < nk) {
      STG_B(cur, 1, t + 2)
      asm volatile("s_waitcnt vmcnt(4)" ::: "memory");
    } else {
      asm volatile("s_waitcnt vmcnt(0)" ::: "memory");
    }
    PREBAR();
    __builtin_amdgcn_s_setprio(1);
#pragma unroll
    for (int mi = 0; mi < 4; ++mi)
#pragma unroll
      for (int ni = 0; ni < 2; ++ni)
#pragma unroll
        for (int ks = 0; ks < 2; ++ks)
          MFMA(acc[4 + mi][ni], af[mi][ks], bf[0][ni][ks]);
    __builtin_amdgcn_s_setprio(0);
    __builtin_amdgcn_s_barrier();
  }

  // epilogue: row = bm*256+wm*128+mf*16+hi*4+j, col = bn*256+wn*64+nf*16+lo
#pragma unroll
  for (int mf = 0; mf < 8; ++mf)
#pragma unroll
    for (int nf = 0; nf < 4; ++nf)
#pragma unroll
      for (int j = 0; j < 4; ++j) {
        size_t idx = (size_t)(bm * 256 + wm * 128 + mf * 16 + hi * 4 + j) * N +
                     bn * 256 + wn * 64 + nf * 16 + lo;
        if (F32OUT) ((float*)C)[idx] = acc[mf][nf][j];
        else        ((u16*)C)[idx]   = f2b(acc[mf][nf][j]);
      }
}

// ---- RoPE + scatter: qkv[b][s][12288] -> q_r,k_r [b][nh][s][hd] ----
__global__ __launch_bounds__(256) void rope_qk(const u16* __restrict__ qkv,
                                               const int* __restrict__ pos,
                                               u16* __restrict__ qr,
                                               u16* __restrict__ kr) {
  __shared__ float cs[64], sn[64];
  const int bs = blockIdx.x;
  const int b = bs >> 11, s = bs & 2047;
  const int tid = threadIdx.x;
  if (tid < 64) {
    float p = (float)pos[bs];
    float freq = __powf(10000.0f, -(float)tid * (1.0f / 64.0f));
    float a = p * freq;
    sn[tid] = sinf(a);
    cs[tid] = cosf(a);
  }
  __syncthreads();
  const u16* src = qkv + (size_t)bs * 12288;
  for (int i = tid; i < 4096; i += 256) {
    int nh = i >> 7, hd = i & 127, f = hd & 63;
    float c = cs[f], sv = sn[f];
    int oth = (hd < 64) ? i + 64 : i - 64;
    size_t dst = ((size_t)(b * NHEAD + nh) * S + s) * HDIM + hd;
    float x = b2f(src[i]), xo = b2f(src[oth]);
    qr[dst] = f2b((hd < 64) ? (x * c - xo * sv) : (x * c + xo * sv));
    float xk = b2f(src[4096 + i]), xko = b2f(src[4096 + oth]);
    kr[dst] = f2b((hd < 64) ? (xk * c - xko * sv) : (xk * c + xko * sv));
  }
}

// ---- V -> MFMA-B-fragment order, per (bh, 64-kv block) ----
__global__ __launch_bounds__(256) void transpose_v(const u16* __restrict__ qkv,
                                                   u16* __restrict__ vt) {
  __shared__ u16 L[64 * 136];
  const int kb = blockIdx.x & 31, bh = blockIdx.x >> 5;
  const int b = bh >> 5, nh = bh & 31;
  const int tid = threadIdx.x;
  const u16* src = qkv + ((size_t)(b * S + kb * 64)) * 12288 + 8192 + nh * 128;
#pragma unroll
  for (int i = 0; i < 4; ++i) {
    int idx = i * 256 + tid, r = idx >> 4, gd = idx & 15;
    *(uint4*)&L[r * 136 + gd * 8] = *(const uint4*)(src + (size_t)r * 12288 + gd * 8);
  }
  __syncthreads();
  u16* dst = vt + ((size_t)bh * S + kb * 64) * 128;
#pragma unroll
  for (int i = 0; i < 4; ++i) {
    int idx = i * 256 + tid;
    int f = idx >> 6, l = idx & 63;
    int ks2 = f >> 3, db = f & 7, hi = l >> 4, lo = l & 15;
    int d = db * 16 + lo;
    int rb = (ks2 * 32 + hi * 8) * 136 + d;
    unsigned e0 = L[rb], e1 = L[rb + 136], e2 = L[rb + 272], e3 = L[rb + 408];
    unsigned e4 = L[rb + 544], e5 = L[rb + 680], e6 = L[rb + 816], e7 = L[rb + 952];
    uint4 o; o.x = e0 | (e1 << 16); o.y = e2 | (e3 << 16);
    o.z = e4 | (e5 << 16); o.w = e6 | (e7 << 16);
    *(uint4*)(dst + (size_t)idx * 8) = o;
  }
}

// ---- flash attention fwd, causal (r7 structure, reverted from QBLK=128) ----
__global__ __launch_bounds__(256, 2) void flash_fwd(const u16* __restrict__ q,
                                                    const u16* __restrict__ k,
                                                    const u16* __restrict__ vt,
                                                    u16* __restrict__ o) {
  __shared__ u16 KB[2][64 * 128];
  __shared__ u16 VB[2][64 * 128];
  __shared__ u16 Ps[4][16 * 64];
  const int nqt = S / 64;
  const int qt = (nqt - 1) - ((int)blockIdx.x % nqt);
  const int bh = blockIdx.x / nqt;
  const int tid = threadIdx.x, lane = tid & 63, w = tid >> 6;
  const int hi = lane >> 4, lo = lane & 15;

  const u16* qg = q + ((size_t)bh * S + qt * 64 + w * 16) * HDIM;
  short8 qf[4];
#pragma unroll
  for (int ks = 0; ks < 4; ++ks) {
    short8 r = *(const short8*)(qg + (size_t)lo * HDIM + ks * 32 + hi * 8);
    union { short8 s; u16 u[8]; } t; t.s = r;
#pragma unroll
    for (int e = 0; e < 8; ++e)
      t.u[e] = f2b(b2f(t.u[e]) * 0.08838834764831845f);
    qf[ks] = t.s;
  }

  float m_i[4], l_i[4];
  f32x4 oacc[8] = {};
#pragma unroll
  for (int j = 0; j < 4; ++j) { m_i[j] = -1e30f; l_i[j] = 0.0f; }

  const u16* kg = k + (size_t)bh * S * HDIM;
  const u16* vg = vt + (size_t)bh * S * HDIM;

#define STAGE(buf, kvbase)                                                  \
  {                                                                         \
    _Pragma("unroll") for (int i = 0; i < 4; ++i) {                         \
      int idx = i * 256 + tid, r = idx >> 4, gd = idx & 15;                 \
      gl16(kg + (size_t)((kvbase) + r) * HDIM + ((gd ^ (r & 7)) * 8),       \
           &KB[buf][idx * 8]);                                              \
    }                                                                       \
    _Pragma("unroll") for (int i = 0; i < 4; ++i) {                         \
      int idx = i * 256 + tid;                                              \
      gl16(vg + (size_t)(kvbase) * HDIM + idx * 8, &VB[buf][idx * 8]);      \
    }                                                                       \
  }

  STAGE(0, 0)
  int cur = 0;
  u16* PsW = &Ps[w][0];

  for (int kvt = 0; kvt <= qt; ++kvt) {
    if (kvt < qt) {
      STAGE(cur ^ 1, (kvt + 1) * 64)
      asm volatile("s_waitcnt vmcnt(8)" ::: "memory");
    } else {
      asm volatile("s_waitcnt vmcnt(0)" ::: "memory");
    }
    __builtin_amdgcn_s_barrier();
    __builtin_amdgcn_sched_barrier(0);
    const u16* Kc = &KB[cur][0];
    const u16* Vc = &VB[cur][0];

    f32x4 sc[4] = {};
#pragma unroll
    for (int ks = 0; ks < 4; ++ks) {
      const int colu = ks * 32 + hi * 8;
#pragma unroll
      for (int cb = 0; cb < 4; ++cb) {
        const int row = cb * 16 + lo;
        short8 kf = *(const short8*)&Kc[row * 128 + (colu ^ ((row & 7) << 3))];
        MFMA(sc[cb], qf[ks], kf);
      }
    }

    const int qrow = qt * 64 + w * 16 + hi * 4;
    const bool diag = (kvt == qt);
#pragma unroll
    for (int cb = 0; cb < 4; ++cb) {
      const int kvc = kvt * 64 + cb * 16 + lo;
#pragma unroll
      for (int j = 0; j < 4; ++j) {
        float sv = sc[cb][j];
        if (diag && kvc > qrow + j) sv = -1e30f;
        sc[cb][j] = sv;
      }
    }
    float rmax[4], rs[4];
#pragma unroll
    for (int j = 0; j < 4; ++j) {
      rmax[j] = fmaxf(fmaxf(sc[0][j], sc[1][j]), fmaxf(sc[2][j], sc[3][j]));
      for (int d = 8; d; d >>= 1) rmax[j] = fmaxf(rmax[j], __shfl_xor(rmax[j], d));
      float mn = fmaxf(m_i[j], rmax[j]);
      float sf = __expf(m_i[j] - mn);
      m_i[j] = mn; l_i[j] *= sf;
#pragma unroll
      for (int db = 0; db < 8; ++db) oacc[db][j] *= sf;
      rs[j] = 0.0f;
    }
#pragma unroll
    for (int cb = 0; cb < 4; ++cb)
#pragma unroll
      for (int j = 0; j < 4; ++j) {
        float p = __expf(sc[cb][j] - m_i[j]);
        sc[cb][j] = p; rs[j] += p;
      }
#pragma unroll
    for (int j = 0; j < 4; ++j) {
      for (int d = 8; d; d >>= 1) rs[j] += __shfl_xor(rs[j], d);
      l_i[j] += rs[j];
    }

#pragma unroll
    for (int cb = 0; cb < 4; ++cb)
#pragma unroll
      for (int j = 0; j < 4; ++j) {
        const int p = hi * 4 + j;
        PsW[p * 64 + ((cb * 16 + lo) ^ ((p & 7) << 3))] = f2b(sc[cb][j]);
      }
    short8 pf0 = *(const short8*)&PsW[lo * 64 + ((hi * 8) ^ ((lo & 7) << 3))];
    short8 pf1 = *(const short8*)&PsW[lo * 64 + ((32 + hi * 8) ^ ((lo & 7) << 3))];

#pragma unroll
    for (int ks2 = 0; ks2 < 2; ++ks2) {
      const short8 pf = ks2 ? pf1 : pf0;
#pragma unroll
      for (int db = 0; db < 8; ++db) {
        short8 vf = *(const short8*)&Vc[((ks2 * 8 + db) * 64 + lane) * 8];
        MFMA(oacc[db], pf, vf);
      }
    }
    __builtin_amdgcn_s_barrier();
    cur ^= 1;
  }

#pragma unroll
  for (int j = 0; j < 4; ++j) {
    float inv = 1.0f / l_i[j];
    int srow = qt * 64 + w * 16 + hi * 4 + j;
    const int b = bh >> 5, nh = bh & 31;
    size_t base = ((size_t)b * S + srow) * H + (size_t)nh * HDIM + lo;
#pragma unroll
    for (int db = 0; db < 8; ++db)
      o[base + db * 16] = f2b(oacc[db][j] * inv);
  }
}

extern "C" void kernel_launch(void* const* d_in, const int* in_sizes, int n_in,
                              void* d_out, int out_size, void* d_ws, size_t ws_size,
                              hipStream_t stream) {
  const int* pos = (const int*)d_in[0];
  const float* hs = (const float*)d_in[1];
  const float* wpack = (const float*)d_in[2];
  const float* wo = (const float*)d_in[3];
  float* out = (float*)d_out;
  char* ws = (char*)d_ws;
  u16* hs_b    = (u16*)(ws + 0UL);          // dead after gemm1 -> reused as v_t
  u16* wpack_b = (u16*)(ws + 33554432UL);
  u16* wo_b    = (u16*)(ws + 134217728UL);
  u16* qkv_b   = (u16*)(ws + 167772160UL);
  u16* q_r     = (u16*)(ws + 268435456UL);
  u16* k_r     = (u16*)(ws + 301989888UL);
  u16* attn_b  = (u16*)(ws + 335544320UL);
  u16* v_t     = hs_b;

  cvt_bf16<<<16384, 256, 0, stream>>>(hs, hs_b);
  cvt_bf16<<<49152, 256, 0, stream>>>(wpack, wpack_b);
  cvt_bf16<<<16384, 256, 0, stream>>>(wo, wo_b);
  gemm256<false><<<768, 512, 0, stream>>>(hs_b, wpack_b, qkv_b, 4096, 12288, 4096);
  rope_qk<<<4096, 256, 0, stream>>>(qkv_b, pos, q_r, k_r);
  transpose_v<<<2048, 256, 0, stream>>>(qkv_b, v_t);
  flash_fwd<<<64 * 32, 256, 0, stream>>>(q_r, k_r, v_t, attn_b);
  gemm256<true><<<256, 512, 0, stream>>>(attn_b, wo_b, out, 4096, 4096, 4096);
}